// Round 7
// baseline (321.148 us; speedup 1.0000x reference)
//
#include <hip/hip_runtime.h>
#include <hip/hip_bf16.h>
#include <hip/hip_fp16.h>

// MeanAggregator: out[n,d] = sum_k mask[n,k]*feat[idx[n,k],d] / max(cnt,1), 0 if cnt==0
// features: [60000,128] f32, idx: [10000,64] i32, mask: [10000,64] i32 (0/1)
//
// R7: XCD-partitioned gather, take 2.
//  - real XCD id via s_getreg(HW_REG_XCC_ID) [m09], not bid%8
//  - persistent blocks + per-partition atomic work counters (zeroed in K1),
//    work-stealing across partitions => correctness independent of mapping
//  - R4-style MLP: 8-deep predicated unrolled gather (2 rows/wave-instr),
//    rare tail loop for cnt>16
//  - fp16 partials (nontemporal stores), f32 combine

#define N_NEIGH 64
#define D_FEAT 128
#define NPART 8

// ---------------- K1: partition the neighbor lists + zero work counters ----
__global__ __launch_bounds__(256) void part_kernel(
    const int* __restrict__ idx,
    const int* __restrict__ mask,
    short* __restrict__ lists,      // [NPART][n_nodes][64] local row ids
    int* __restrict__ cnts,         // [NPART][n_nodes]
    int* __restrict__ wctr,         // [NPART] work counters for K2
    int n_nodes, int rows_per_part)
{
    const int tid = threadIdx.x;
    if (blockIdx.x == 0 && tid < NPART) wctr[tid] = 0;

    const int node = blockIdx.x * 4 + (tid >> 6);   // one wave per node
    const int lane = tid & 63;
    if (node >= n_nodes) return;                    // wave-uniform exit

    const int i = idx[(long)node * N_NEIGH + lane];
    const int m = mask[(long)node * N_NEIGH + lane];
    const int p = i / rows_per_part;

    #pragma unroll
    for (int p0 = 0; p0 < NPART; ++p0) {
        const bool sel = (m != 0) && (p == p0);
        const unsigned long long bal = __ballot(sel);
        if (sel) {
            const int pos = __popcll(bal & ((1ull << lane) - 1ull));
            lists[((long)p0 * n_nodes + node) * N_NEIGH + pos] =
                (short)(i - p0 * rows_per_part);
        }
        if (lane == 0) cnts[p0 * n_nodes + node] = (int)__popcll(bal);
    }
}

// ---------------- K2: persistent per-XCD gather ----------------
__global__ __launch_bounds__(256) void gather_part2(
    const float* __restrict__ feat,
    const short* __restrict__ lists,
    const int* __restrict__ cnts,
    unsigned long long* __restrict__ partials,  // [NPART][n_nodes][32] u64 (=128 halves)
    int* __restrict__ wctr,
    int n_nodes, int rows_per_part)
{
    int xcc;
    asm volatile("s_getreg_b32 %0, hwreg(HW_REG_XCC_ID)" : "=s"(xcc));
    xcc &= 7;

    const int tid = threadIdx.x;
    const int w = tid >> 6;                  // wave 0..3
    const int lane = tid & 63;
    const int slot = lane >> 5;              // 2 rows per wave-instr
    const int d4 = lane & 31;                // 16B chunk of the 512B row

    __shared__ int s_n0;

    // Own partition first; steal from others once exhausted (correctness
    // never depends on the XCD mapping, only locality does).
    for (int pp = 0; pp < NPART; ++pp) {
        const int p = (xcc + pp) & (NPART - 1);
        const float* fpart = feat + (long)p * rows_per_part * D_FEAT;

        for (;;) {
            if (tid == 0) s_n0 = atomicAdd(&wctr[p], 8);
            __syncthreads();
            const int n0 = s_n0;
            __syncthreads();
            if (n0 >= n_nodes) break;

            #pragma unroll
            for (int h = 0; h < 2; ++h) {
                const int node = n0 + (w << 1) + h;
                if (node >= n_nodes) continue;
                const long cell = (long)p * n_nodes + node;
                const int cnt = cnts[cell];

                // whole 64-entry list into one reg/lane (128B coalesced);
                // entries >= cnt are garbage but never dereferenced.
                int myrow = (int)lists[cell * N_NEIGH + lane];

                float4 acc = make_float4(0.f, 0.f, 0.f, 0.f);
                #pragma unroll
                for (int rr = 0; rr < 8; ++rr) {
                    const int r = slot + rr * 2;
                    if (r < cnt) {
                        const int row = __shfl(myrow, r);
                        const float4 v = ((const float4*)(fpart + (long)row * D_FEAT))[d4];
                        acc.x += v.x; acc.y += v.y; acc.z += v.z; acc.w += v.w;
                    }
                }
                if (__any(cnt > 16)) {                 // rare (Binomial(32,1/8))
                    for (int r = 16 + slot; r < cnt; r += 2) {
                        const int row = __shfl(myrow, r);
                        const float4 v = ((const float4*)(fpart + (long)row * D_FEAT))[d4];
                        acc.x += v.x; acc.y += v.y; acc.z += v.z; acc.w += v.w;
                    }
                }

                acc.x += __shfl_xor(acc.x, 32);
                acc.y += __shfl_xor(acc.y, 32);
                acc.z += __shfl_xor(acc.z, 32);
                acc.w += __shfl_xor(acc.w, 32);

                if (slot == 0) {
                    __half2 h01 = __floats2half2_rn(acc.x, acc.y);
                    __half2 h23 = __floats2half2_rn(acc.z, acc.w);
                    unsigned long long pk =
                        (unsigned long long)(*reinterpret_cast<unsigned*>(&h01)) |
                        ((unsigned long long)(*reinterpret_cast<unsigned*>(&h23)) << 32);
                    __builtin_nontemporal_store(pk, partials + cell * 32 + d4);
                }
            }
        }
    }
}

// ---------------- K3: combine partials ----------------
__global__ __launch_bounds__(256) void combine_kernel(
    const unsigned long long* __restrict__ partials,  // [NPART][n_nodes][32] u64
    const int* __restrict__ cnts,
    float* __restrict__ out, int n_nodes)
{
    const int tid = threadIdx.x;
    const int node = blockIdx.x * 8 + (tid >> 5);  // 32 threads per node
    const int q = tid & 31;                        // which u64 (4 halves)
    if (node >= n_nodes) return;

    float4 acc = make_float4(0.f, 0.f, 0.f, 0.f);
    int cnt = 0;
    #pragma unroll
    for (int p = 0; p < NPART; ++p) {
        const long cell = (long)p * n_nodes + node;
        cnt += cnts[cell];
        const unsigned long long pk = partials[cell * 32 + q];
        unsigned lo = (unsigned)pk;
        unsigned hi = (unsigned)(pk >> 32);
        const float2 v01 = __half22float2(*reinterpret_cast<__half2*>(&lo));
        const float2 v23 = __half22float2(*reinterpret_cast<__half2*>(&hi));
        acc.x += v01.x; acc.y += v01.y; acc.z += v23.x; acc.w += v23.y;
    }
    const float inv = (cnt > 0) ? (1.0f / (float)cnt) : 0.0f;
    acc.x *= inv; acc.y *= inv; acc.z *= inv; acc.w *= inv;
    ((float4*)(out + (long)node * D_FEAT))[q] = acc;
}

// ---------------- Fallback (ws too small): R4 single-kernel gather --------
__global__ __launch_bounds__(256) void mean_agg_f32c(
    const float* __restrict__ feat,
    const int* __restrict__ idx,
    const int* __restrict__ mask,
    float* __restrict__ out,
    int n_nodes)
{
    const int node = blockIdx.x;

    __shared__ int s_cidx[N_NEIGH];
    __shared__ int s_cnt;
    __shared__ float4 s_part[4][32];

    const int tid = threadIdx.x;

    if (tid < 64) {
        const int i = idx[(long)node * N_NEIGH + tid];
        const int m = mask[(long)node * N_NEIGH + tid];
        const unsigned long long bal = __ballot(m != 0);
        const int pos = __popcll(bal & ((1ull << tid) - 1ull));
        if (m) s_cidx[pos] = i;
        if (tid == 0) s_cnt = (int)__popcll(bal);
    }
    __syncthreads();

    const int cnt = s_cnt;
    const int slot = tid >> 5;
    const int d4   = tid & 31;

    float4 acc = make_float4(0.f, 0.f, 0.f, 0.f);
    #pragma unroll
    for (int rr = 0; rr < 8; ++rr) {
        const int r = slot + rr * 8;
        if (r < cnt) {
            const float4 v = ((const float4*)(feat + (long)s_cidx[r] * D_FEAT))[d4];
            acc.x += v.x; acc.y += v.y; acc.z += v.z; acc.w += v.w;
        }
    }
    acc.x += __shfl_xor(acc.x, 32);
    acc.y += __shfl_xor(acc.y, 32);
    acc.z += __shfl_xor(acc.z, 32);
    acc.w += __shfl_xor(acc.w, 32);

    const int wv = tid >> 6;
    if ((tid & 63) < 32) s_part[wv][d4] = acc;
    __syncthreads();

    if (tid < 32) {
        const float4 p0 = s_part[0][tid];
        const float4 p1 = s_part[1][tid];
        const float4 p2 = s_part[2][tid];
        const float4 p3 = s_part[3][tid];
        float4 t;
        t.x = (p0.x + p1.x) + (p2.x + p3.x);
        t.y = (p0.y + p1.y) + (p2.y + p3.y);
        t.z = (p0.z + p1.z) + (p2.z + p3.z);
        t.w = (p0.w + p1.w) + (p2.w + p3.w);
        const float inv = (cnt > 0) ? (1.0f / (float)cnt) : 0.0f;
        t.x *= inv; t.y *= inv; t.z *= inv; t.w *= inv;
        ((float4*)(out + (long)node * D_FEAT))[tid] = t;
    }
}

extern "C" void kernel_launch(void* const* d_in, const int* in_sizes, int n_in,
                              void* d_out, int out_size, void* d_ws, size_t ws_size,
                              hipStream_t stream) {
    const float* feat = (const float*)d_in[0];
    const int*   idx  = (const int*)d_in[1];
    const int*   mask = (const int*)d_in[2];
    float*       out  = (float*)d_out;

    const int n_nodes = in_sizes[1] / N_NEIGH;        // 10000
    const int n_src   = in_sizes[0] / D_FEAT;         // 60000
    const int rpp     = (n_src + NPART - 1) / NPART;  // 7500

    const size_t sz_lists = (size_t)NPART * n_nodes * N_NEIGH * sizeof(short);
    const size_t sz_cnts  = (size_t)NPART * n_nodes * sizeof(int);
    const size_t sz_part  = (size_t)NPART * n_nodes * D_FEAT * sizeof(__half);
    const size_t sz_wctr  = (size_t)NPART * sizeof(int);
    const size_t off_cnts = (sz_lists + 255) & ~(size_t)255;
    const size_t off_part = (off_cnts + sz_cnts + 255) & ~(size_t)255;
    const size_t off_wctr = (off_part + sz_part + 255) & ~(size_t)255;
    const size_t need = off_wctr + sz_wctr;

    if (ws_size >= need) {
        short* lists = (short*)d_ws;
        int*   cnts  = (int*)((char*)d_ws + off_cnts);
        unsigned long long* partials = (unsigned long long*)((char*)d_ws + off_part);
        int*   wctr  = (int*)((char*)d_ws + off_wctr);

        part_kernel<<<(n_nodes + 3) / 4, 256, 0, stream>>>(idx, mask, lists, cnts, wctr, n_nodes, rpp);
        gather_part2<<<2048, 256, 0, stream>>>(feat, lists, cnts, partials, wctr, n_nodes, rpp);
        combine_kernel<<<(n_nodes + 7) / 8, 256, 0, stream>>>(partials, cnts, out, n_nodes);
    } else {
        mean_agg_f32c<<<n_nodes, 256, 0, stream>>>(feat, idx, mask, out, n_nodes);
    }
}

// Round 8
// 37.500 us; speedup vs baseline: 8.5638x; 8.5638x over previous
//
#include <hip/hip_runtime.h>
#include <hip/hip_bf16.h>
#include <hip/hip_fp16.h>

// MeanAggregator: out[n,d] = sum_k mask[n,k]*feat[idx[n,k],d] / max(cnt,1), 0 if cnt==0
// features: [60000,128] f32, idx: [10000,64] i32, mask: [10000,64] i32 (0/1)
//
// R8: XCD-partitioned gather, static assignment (no atomics).
// R7 evidence: XCC-steered partitions collapse FETCH 75->23.6 MB (locality
// works), but atomic work-stealing cost 305 us of stall. Here: partition
// p = bid&7 (blockIdx round-robins across XCDs), node-group = bid>>3.
// Inner body = R7's 8-deep predicated unrolled MLP gather.
//   K1 partition: split each node's masked neighbors into 8 per-partition lists
//   K2 gather: 1250x8 static blocks; fp16 partials (nontemporal stores)
//   K3 combine: sum 8 partials, divide by count, store f32

#define N_NEIGH 64
#define D_FEAT 128
#define NPART 8

// ---------------- K1: partition the neighbor lists ----------------
__global__ __launch_bounds__(256) void part_kernel(
    const int* __restrict__ idx,
    const int* __restrict__ mask,
    short* __restrict__ lists,      // [NPART][n_nodes][64] local row ids
    int* __restrict__ cnts,         // [NPART][n_nodes]
    int n_nodes, int rows_per_part)
{
    const int tid = threadIdx.x;
    const int node = blockIdx.x * 4 + (tid >> 6);   // one wave per node
    const int lane = tid & 63;
    if (node >= n_nodes) return;                    // wave-uniform exit

    const int i = idx[(long)node * N_NEIGH + lane];
    const int m = mask[(long)node * N_NEIGH + lane];
    const int p = i / rows_per_part;

    #pragma unroll
    for (int p0 = 0; p0 < NPART; ++p0) {
        const bool sel = (m != 0) && (p == p0);
        const unsigned long long bal = __ballot(sel);
        if (sel) {
            const int pos = __popcll(bal & ((1ull << lane) - 1ull));
            lists[((long)p0 * n_nodes + node) * N_NEIGH + pos] =
                (short)(i - p0 * rows_per_part);
        }
        if (lane == 0) cnts[p0 * n_nodes + node] = (int)__popcll(bal);
    }
}

// ---------------- K2: static per-partition gather ----------------
__global__ __launch_bounds__(256) void gather_static(
    const float* __restrict__ feat,
    const short* __restrict__ lists,
    const int* __restrict__ cnts,
    unsigned long long* __restrict__ partials,  // [NPART][n_nodes][32] u64 (=128 halves)
    int n_nodes, int rows_per_part)
{
    const int p = blockIdx.x & (NPART - 1);   // partition; bid%8 round-robins XCDs
    const int gbase = (blockIdx.x >> 3) * 8;  // 8-node group
    const int tid = threadIdx.x;
    const int w = tid >> 6;                   // wave 0..3
    const int lane = tid & 63;
    const int slot = lane >> 5;               // 2 rows per wave-instr
    const int d4 = lane & 31;                 // 16B chunk of the 512B row
    const float* fpart = feat + (long)p * rows_per_part * D_FEAT;

    #pragma unroll
    for (int h = 0; h < 2; ++h) {
        const int node = gbase + (w << 1) + h;
        if (node >= n_nodes) continue;
        const long cell = (long)p * n_nodes + node;
        const int cnt = cnts[cell];

        // whole 64-entry list into one reg/lane (128B coalesced);
        // entries >= cnt are garbage but never dereferenced.
        const int myrow = (int)lists[cell * N_NEIGH + lane];

        float4 acc = make_float4(0.f, 0.f, 0.f, 0.f);
        #pragma unroll
        for (int rr = 0; rr < 8; ++rr) {
            const int r = slot + rr * 2;
            if (r < cnt) {
                const int row = __shfl(myrow, r);
                const float4 v = ((const float4*)(fpart + (long)row * D_FEAT))[d4];
                acc.x += v.x; acc.y += v.y; acc.z += v.z; acc.w += v.w;
            }
        }
        if (__any(cnt > 16)) {                 // rare tail (cnt ~ Binom(64, mask/8))
            for (int r = 16 + slot; r < cnt; r += 2) {
                const int row = __shfl(myrow, r);
                const float4 v = ((const float4*)(fpart + (long)row * D_FEAT))[d4];
                acc.x += v.x; acc.y += v.y; acc.z += v.z; acc.w += v.w;
            }
        }

        acc.x += __shfl_xor(acc.x, 32);
        acc.y += __shfl_xor(acc.y, 32);
        acc.z += __shfl_xor(acc.z, 32);
        acc.w += __shfl_xor(acc.w, 32);

        if (slot == 0) {
            __half2 h01 = __floats2half2_rn(acc.x, acc.y);
            __half2 h23 = __floats2half2_rn(acc.z, acc.w);
            unsigned long long pk =
                (unsigned long long)(*reinterpret_cast<unsigned*>(&h01)) |
                ((unsigned long long)(*reinterpret_cast<unsigned*>(&h23)) << 32);
            // nontemporal: don't evict the table slice from L2
            __builtin_nontemporal_store(pk, partials + cell * 32 + d4);
        }
    }
}

// ---------------- K3: combine partials ----------------
__global__ __launch_bounds__(256) void combine_kernel(
    const unsigned long long* __restrict__ partials,  // [NPART][n_nodes][32] u64
    const int* __restrict__ cnts,
    float* __restrict__ out, int n_nodes)
{
    const int tid = threadIdx.x;
    const int node = blockIdx.x * 8 + (tid >> 5);  // 32 threads per node
    const int q = tid & 31;                        // which u64 (4 halves)
    if (node >= n_nodes) return;

    float4 acc = make_float4(0.f, 0.f, 0.f, 0.f);
    int cnt = 0;
    #pragma unroll
    for (int p = 0; p < NPART; ++p) {
        const long cell = (long)p * n_nodes + node;
        cnt += cnts[cell];
        const unsigned long long pk = partials[cell * 32 + q];
        unsigned lo = (unsigned)pk;
        unsigned hi = (unsigned)(pk >> 32);
        const float2 v01 = __half22float2(*reinterpret_cast<__half2*>(&lo));
        const float2 v23 = __half22float2(*reinterpret_cast<__half2*>(&hi));
        acc.x += v01.x; acc.y += v01.y; acc.z += v23.x; acc.w += v23.y;
    }
    const float inv = (cnt > 0) ? (1.0f / (float)cnt) : 0.0f;
    acc.x *= inv; acc.y *= inv; acc.z *= inv; acc.w *= inv;
    ((float4*)(out + (long)node * D_FEAT))[q] = acc;
}

// ---------------- Fallback (ws too small): R4 single-kernel gather --------
__global__ __launch_bounds__(256) void mean_agg_f32c(
    const float* __restrict__ feat,
    const int* __restrict__ idx,
    const int* __restrict__ mask,
    float* __restrict__ out,
    int n_nodes)
{
    const int node = blockIdx.x;

    __shared__ int s_cidx[N_NEIGH];
    __shared__ int s_cnt;
    __shared__ float4 s_part[4][32];

    const int tid = threadIdx.x;

    if (tid < 64) {
        const int i = idx[(long)node * N_NEIGH + tid];
        const int m = mask[(long)node * N_NEIGH + tid];
        const unsigned long long bal = __ballot(m != 0);
        const int pos = __popcll(bal & ((1ull << tid) - 1ull));
        if (m) s_cidx[pos] = i;
        if (tid == 0) s_cnt = (int)__popcll(bal);
    }
    __syncthreads();

    const int cnt = s_cnt;
    const int slot = tid >> 5;
    const int d4   = tid & 31;

    float4 acc = make_float4(0.f, 0.f, 0.f, 0.f);
    #pragma unroll
    for (int rr = 0; rr < 8; ++rr) {
        const int r = slot + rr * 8;
        if (r < cnt) {
            const float4 v = ((const float4*)(feat + (long)s_cidx[r] * D_FEAT))[d4];
            acc.x += v.x; acc.y += v.y; acc.z += v.z; acc.w += v.w;
        }
    }
    acc.x += __shfl_xor(acc.x, 32);
    acc.y += __shfl_xor(acc.y, 32);
    acc.z += __shfl_xor(acc.z, 32);
    acc.w += __shfl_xor(acc.w, 32);

    const int wv = tid >> 6;
    if ((tid & 63) < 32) s_part[wv][d4] = acc;
    __syncthreads();

    if (tid < 32) {
        const float4 p0 = s_part[0][tid];
        const float4 p1 = s_part[1][tid];
        const float4 p2 = s_part[2][tid];
        const float4 p3 = s_part[3][tid];
        float4 t;
        t.x = (p0.x + p1.x) + (p2.x + p3.x);
        t.y = (p0.y + p1.y) + (p2.y + p3.y);
        t.z = (p0.z + p1.z) + (p2.z + p3.z);
        t.w = (p0.w + p1.w) + (p2.w + p3.w);
        const float inv = (cnt > 0) ? (1.0f / (float)cnt) : 0.0f;
        t.x *= inv; t.y *= inv; t.z *= inv; t.w *= inv;
        ((float4*)(out + (long)node * D_FEAT))[tid] = t;
    }
}

extern "C" void kernel_launch(void* const* d_in, const int* in_sizes, int n_in,
                              void* d_out, int out_size, void* d_ws, size_t ws_size,
                              hipStream_t stream) {
    const float* feat = (const float*)d_in[0];
    const int*   idx  = (const int*)d_in[1];
    const int*   mask = (const int*)d_in[2];
    float*       out  = (float*)d_out;

    const int n_nodes = in_sizes[1] / N_NEIGH;        // 10000
    const int n_src   = in_sizes[0] / D_FEAT;         // 60000
    const int rpp     = (n_src + NPART - 1) / NPART;  // 7500

    const size_t sz_lists = (size_t)NPART * n_nodes * N_NEIGH * sizeof(short);
    const size_t sz_cnts  = (size_t)NPART * n_nodes * sizeof(int);
    const size_t sz_part  = (size_t)NPART * n_nodes * D_FEAT * sizeof(__half);
    const size_t off_cnts = (sz_lists + 255) & ~(size_t)255;
    const size_t off_part = (off_cnts + sz_cnts + 255) & ~(size_t)255;
    const size_t need = off_part + sz_part;

    if (ws_size >= need) {
        short* lists = (short*)d_ws;
        int*   cnts  = (int*)((char*)d_ws + off_cnts);
        unsigned long long* partials = (unsigned long long*)((char*)d_ws + off_part);

        const int ngrp = (n_nodes + 7) / 8;           // 1250
        part_kernel<<<(n_nodes + 3) / 4, 256, 0, stream>>>(idx, mask, lists, cnts, n_nodes, rpp);
        gather_static<<<ngrp * NPART, 256, 0, stream>>>(feat, lists, cnts, partials, n_nodes, rpp);
        combine_kernel<<<(n_nodes + 7) / 8, 256, 0, stream>>>(partials, cnts, out, n_nodes);
    } else {
        mean_agg_f32c<<<n_nodes, 256, 0, stream>>>(feat, idx, mask, out, n_nodes);
    }
}